// Round 6
// baseline (114.254 us; speedup 1.0000x reference)
//
#include <hip/hip_runtime.h>
#include <stdint.h>

typedef short bf16x8 __attribute__((ext_vector_type(8)));
typedef float f32x4 __attribute__((ext_vector_type(4)));

__device__ __forceinline__ unsigned short f2bf(float f) {
  unsigned u = __float_as_uint(f);
  u += 0x7fffu + ((u >> 16) & 1u);   // RNE round to bf16
  return (unsigned short)(u >> 16);
}
__device__ __forceinline__ unsigned umax_(unsigned a, unsigned b) { return a > b ? a : b; }

// ---- fused prep(emb->bf16 + half||e||^2) + prez(z -> fragment-tiled bf16 + sum z^2)
// zb layout: per 16-row tile (8192 B): offset = ((kk*4+l4)*16 + l15)*16B
//   holds row (tile*16+l15), c in [kk*32+l4*8, +8)  -> k_main A-load = base+lane*16
__global__ __launch_bounds__(256) void k_pre(const float* __restrict__ z,
                                             const float* __restrict__ emb,
                                             unsigned short* __restrict__ embb,
                                             float* __restrict__ h2,
                                             unsigned short* __restrict__ zb,
                                             float* __restrict__ acc) {
  __shared__ unsigned lds[64 * 128];   // [h][cp ^ (h&28)]
  __shared__ float rsum[4];
  const int t = threadIdx.x;
  const int bid = blockIdx.x;

  if (bid >= 512) {            // ---- prep branch (128 blocks) ----
    const int n = (bid - 512) * 8 + (t >> 5);
    const int c0 = (t & 31) * 8;
    const float* src = emb + (size_t)n * 256 + c0;
    float s = 0.f;
    union { bf16x8 v; unsigned short u[8]; } pk;
#pragma unroll
    for (int i = 0; i < 8; ++i) {
      float f = src[i];
      s += f * f;
      pk.u[i] = f2bf(f);
    }
    *(bf16x8*)(embb + (size_t)n * 256 + c0) = pk.v;
#pragma unroll
    for (int m = 1; m < 32; m <<= 1) s += __shfl_xor(s, m);
    if ((t & 31) == 0) h2[n] = 0.5f * s;
    return;
  }

  // ---- prez branch (512 blocks): 64 hw-rows x 256 c ----
  const int b = bid >> 4, hwg = bid & 15;
  const int tc = t >> 4, h4 = (t & 15) * 4;
  const float* zp = z + (size_t)b * 262144 + hwg * 64;
  float ss = 0.f;
#pragma unroll
  for (int p = 0; p < 8; ++p) {
    const int cp = p * 16 + tc;                       // c-pair index 0..127
    const float4 v0 = *(const float4*)(zp + (size_t)(2 * cp) * 1024 + h4);
    const float4 v1 = *(const float4*)(zp + (size_t)(2 * cp + 1) * 1024 + h4);
    ss += v0.x * v0.x + v0.y * v0.y + v0.z * v0.z + v0.w * v0.w
        + v1.x * v1.x + v1.y * v1.y + v1.z * v1.z + v1.w * v1.w;
    const unsigned w0 = ((unsigned)f2bf(v1.x) << 16) | (unsigned)f2bf(v0.x);
    const unsigned w1 = ((unsigned)f2bf(v1.y) << 16) | (unsigned)f2bf(v0.y);
    const unsigned w2 = ((unsigned)f2bf(v1.z) << 16) | (unsigned)f2bf(v0.z);
    const unsigned w3 = ((unsigned)f2bf(v1.w) << 16) | (unsigned)f2bf(v0.w);
    lds[(h4 + 0) * 128 + (cp ^ ((h4 + 0) & 28))] = w0;
    lds[(h4 + 1) * 128 + (cp ^ ((h4 + 1) & 28))] = w1;
    lds[(h4 + 2) * 128 + (cp ^ ((h4 + 2) & 28))] = w2;
    lds[(h4 + 3) * 128 + (cp ^ ((h4 + 3) & 28))] = w3;
  }
#pragma unroll
  for (int m = 1; m < 64; m <<= 1) ss += __shfl_xor(ss, m);
  if ((t & 63) == 0) rsum[t >> 6] = ss;
  __syncthreads();
  if (t == 0) atomicAdd(acc, rsum[0] + rsum[1] + rsum[2] + rsum[3]);

  // write out in fragment-tiled order; stores perfectly coalesced
  unsigned* zbd = (unsigned*)zb;
  const size_t base_dw = ((size_t)b * 1024 + hwg * 64) * 128;
  const int l15 = t & 15, fr = t >> 4;                // fr 0..15
#pragma unroll
  for (int tile = 0; tile < 4; ++tile) {
    const int r = tile * 16 + l15;
#pragma unroll
    for (int half = 0; half < 2; ++half) {
      const int frag = fr + half * 16;                // 0..31 = kk*4+l4
      const int d = (frag >> 2) * 16 + (frag & 3) * 4;
      uint4 v = *(const uint4*)(&lds[r * 128 + (d ^ (r & 28))]);
      *(uint4*)(zbd + base_dw + tile * 2048 + frag * 64 + l15 * 4) = v;
    }
  }
}

// ---- main: B(64 emb) in LDS once, A streamed via contiguous 1KB loads,
// depth-2 register ring, no in-loop barriers, plain part[] stores.
// grid 1024 = 16 ch x 64 rg (bid = ch*64+rg -> same rg same XCD), 4 blocks/CU.
__global__ __launch_bounds__(256, 4) void k_main(
    const unsigned short* __restrict__ zb, const unsigned short* __restrict__ embb,
    const float* __restrict__ h2, unsigned* __restrict__ part) {

  __shared__ __align__(16) unsigned short lB[64 * 256];   // 32 KB

  const int t = threadIdx.x;
  const int lane = t & 63;
  const int w = t >> 6;
  const int l15 = lane & 15;
  const int l4 = lane >> 4;
  const int rg = blockIdx.x & 63;
  const int ch = blockIdx.x >> 6;
  const int cb = ch * 64;

  {
    const unsigned short* base = embb + (size_t)cb * 256;
#pragma unroll
    for (int rd = 0; rd < 8; ++rd) {
      const int nl = rd * 8 + (t >> 5);
      const int p = t & 31;
      const int kc = p ^ (nl & 7);
      const unsigned short* g = base + (size_t)nl * 256 + kc * 8;
      char* l = (char*)lB + rd * 4096 + w * 1024;
      __builtin_amdgcn_global_load_lds((const __attribute__((address_space(1))) void*)g,
                                       (__attribute__((address_space(3))) void*)l,
                                       16, 0, 0);
    }
  }
  float hneg[4];
  unsigned cio[4];
#pragma unroll
  for (int ni = 0; ni < 4; ++ni) {
    hneg[ni] = -1.0f - h2[cb + ni * 16 + l15];   // shift scores to t-1 < 0
    cio[ni] = (unsigned)(1023 - (cb + ni * 16 + l15));
  }
  asm volatile("s_waitcnt vmcnt(0)" ::: "memory");
  __syncthreads();   // the only barrier

  // wave w owns tiles w*8 .. w*8+7 (128 rows); tile stride 8192 B, kk stride 1024 B
  const char* Aw = (const char*)zb + (size_t)rg * 262144 + (size_t)w * 65536 + lane * 16;

  bf16x8 ring[3][2];
  f32x4 acc[2][4];
  ring[0][0] = *(const bf16x8*)(Aw + 0 * 8192 + 0 * 1024);
  ring[0][1] = *(const bf16x8*)(Aw + 1 * 8192 + 0 * 1024);
  ring[1][0] = *(const bf16x8*)(Aw + 0 * 8192 + 1 * 1024);
  ring[1][1] = *(const bf16x8*)(Aw + 1 * 8192 + 1 * 1024);

#pragma unroll
  for (int s = 0; s < 32; ++s) {
    const int pass = s >> 3, kk = s & 7;
    if (kk == 0) {
#pragma unroll
      for (int mi = 0; mi < 2; ++mi)
#pragma unroll
        for (int ni = 0; ni < 4; ++ni)
#pragma unroll
          for (int q = 0; q < 4; ++q) acc[mi][ni][q] = hneg[ni];
    }
    if (s + 2 < 32) {
      const int s2 = s + 2, p2 = s2 >> 3, k2 = s2 & 7;
      ring[s2 % 3][0] = *(const bf16x8*)(Aw + (p2 * 2 + 0) * 8192 + k2 * 1024);
      ring[s2 % 3][1] = *(const bf16x8*)(Aw + (p2 * 2 + 1) * 8192 + k2 * 1024);
    }
    bf16x8 bf[4];
#pragma unroll
    for (int ni = 0; ni < 4; ++ni) {
      const int n = ni * 16 + l15;
      const int p = (kk * 4 + l4) ^ (n & 7);
      bf[ni] = *(const bf16x8*)((const char*)lB + n * 512 + p * 16);
    }
#pragma unroll
    for (int ni = 0; ni < 4; ++ni) {
      acc[0][ni] = __builtin_amdgcn_mfma_f32_16x16x32_bf16(ring[s % 3][0], bf[ni], acc[0][ni], 0, 0, 0);
      acc[1][ni] = __builtin_amdgcn_mfma_f32_16x16x32_bf16(ring[s % 3][1], bf[ni], acc[1][ni], 0, 0, 0);
    }
    if (kk == 7) {   // fold 64 cols -> per-row best key, store per-chunk partial
#pragma unroll
      for (int mi = 0; mi < 2; ++mi)
#pragma unroll
        for (int j = 0; j < 4; ++j) {
          unsigned kb = (~__float_as_uint(acc[mi][0][j]) & 0xFFFFFC00u) | cio[0];
          kb = umax_(kb, (~__float_as_uint(acc[mi][1][j]) & 0xFFFFFC00u) | cio[1]);
          kb = umax_(kb, (~__float_as_uint(acc[mi][2][j]) & 0xFFFFFC00u) | cio[2]);
          kb = umax_(kb, (~__float_as_uint(acc[mi][3][j]) & 0xFFFFFC00u) | cio[3]);
          kb = umax_(kb, (unsigned)__builtin_amdgcn_update_dpp(0, (int)kb, 0xB1, 0xF, 0xF, true));
          kb = umax_(kb, (unsigned)__builtin_amdgcn_update_dpp(0, (int)kb, 0x4E, 0xF, 0xF, true));
          kb = umax_(kb, (unsigned)__builtin_amdgcn_update_dpp(0, (int)kb, 0x141, 0xF, 0xF, true));
          kb = umax_(kb, (unsigned)__builtin_amdgcn_update_dpp(0, (int)kb, 0x140, 0xF, 0xF, true));
          if (l15 == 0) {
            const int row = rg * 512 + (w * 8 + pass * 2 + mi) * 16 + l4 * 4 + j;
            part[(size_t)row * 16 + ch] = kb;
          }
        }
    }
  }
}

// ---- final: merge 16 partials/row, gather emb, transposed write, loss ------
__global__ __launch_bounds__(256) void k_final(const unsigned* __restrict__ part,
                                               const float* __restrict__ emb,
                                               float* __restrict__ out,
                                               float* __restrict__ acc,
                                               unsigned* __restrict__ done2,
                                               float* __restrict__ lossp) {
  __shared__ int sidx[64];
  __shared__ float lds[64 * 68];
  const int t = threadIdx.x;
  const int lane = t & 63;
  const int w = t >> 6;
  const int l15 = lane & 15;
  const int l4 = lane >> 4;
  const int b = blockIdx.x >> 4, hwg = blockIdx.x & 15;
  const int rowb = b * 1024 + hwg * 64;

  if (t < 64) {
    const uint4* pp = (const uint4*)part + (size_t)(rowb + t) * 4;
    unsigned kb = 0;
#pragma unroll
    for (int i = 0; i < 4; ++i) {
      const uint4 v = pp[i];
      kb = umax_(kb, umax_(umax_(v.x, v.y), umax_(v.z, v.w)));
    }
    sidx[t] = 1023 - (int)(kb & 1023u);
    float s = __uint_as_float(~kb) + 1.0f;   // decode t' and unshift
#pragma unroll
    for (int m = 1; m < 64; m <<= 1) s += __shfl_xor(s, m);
    if (t == 0) atomicAdd(acc, -2.f * s);
  }
  __syncthreads();

  const int hw = t & 63, cq = t >> 6;
  const float* ep = emb + (size_t)sidx[hw] * 256;
  float* ob = out + (size_t)b * 262144 + hwg * 64;
#pragma unroll
  for (int cc = 0; cc < 4; ++cc) {
    const int c0 = cc * 64 + cq * 16;
#pragma unroll
    for (int i = 0; i < 4; ++i) {
      const float4 v = *(const float4*)(ep + c0 + i * 4);
      lds[(cq * 16 + i * 4 + 0) * 68 + hw] = v.x;
      lds[(cq * 16 + i * 4 + 1) * 68 + hw] = v.y;
      lds[(cq * 16 + i * 4 + 2) * 68 + hw] = v.z;
      lds[(cq * 16 + i * 4 + 3) * 68 + hw] = v.w;
    }
    __syncthreads();
#pragma unroll
    for (int i = 0; i < 4; ++i) {
      const int c = w * 16 + i * 4 + l4;
      const float4 vv = *(const float4*)(&lds[c * 68 + l15 * 4]);
      *(float4*)(ob + (size_t)(cc * 64 + c) * 1024 + l15 * 4) = vv;
    }
    __syncthreads();
  }

  if (t == 0) {
    __threadfence();
    const unsigned old = atomicAdd(done2, 1u);
    if (old == 511u) {
      const float tot = atomicAdd(acc, 0.f);
      lossp[0] = 1.25f * tot * (1.0f / 8388608.0f);
    }
  }
}

extern "C" void kernel_launch(void* const* d_in, const int* in_sizes, int n_in,
                              void* d_out, int out_size, void* d_ws, size_t ws_size,
                              hipStream_t stream) {
  (void)in_sizes; (void)n_in; (void)ws_size;
  const float* z   = (const float*)d_in[0];
  const float* emb = (const float*)d_in[1];
  float* out = (float*)d_out;
  char* ws = (char*)d_ws;
  unsigned short* embb = (unsigned short*)ws;                    // 512 KB
  float* h2    = (float*)(ws + 524288);                          // 4 KB
  float* acc   = (float*)(ws + 528384);                          // 4 B
  unsigned* done2 = (unsigned*)(ws + 528388);                    // 4 B
  unsigned short* zb = (unsigned short*)(ws + (1 << 20));        // 16 MB
  unsigned* part = (unsigned*)(ws + (1 << 20) + 16777216);       // 2 MB

  hipMemsetAsync(ws + 528384, 0, 8, stream);
  hipLaunchKernelGGL(k_pre, dim3(640), dim3(256), 0, stream, z, emb, embb, h2, zb, acc);
  hipLaunchKernelGGL(k_main, dim3(1024), dim3(256), 0, stream, zb, embb, h2, part);
  hipLaunchKernelGGL(k_final, dim3(512), dim3(256), 0, stream, part, emb, out, acc, done2,
                     out + (size_t)out_size - 1);
}

// Round 7
// 73.539 us; speedup vs baseline: 1.5536x; 1.5536x over previous
//
#include <hip/hip_runtime.h>
#include <stdint.h>

typedef short bf16x8 __attribute__((ext_vector_type(8)));
typedef float f32x4 __attribute__((ext_vector_type(4)));

__device__ __forceinline__ unsigned short f2bf(float f) {
  unsigned u = __float_as_uint(f);
  u += 0x7fffu + ((u >> 16) & 1u);   // RNE round to bf16
  return (unsigned short)(u >> 16);
}
__device__ __forceinline__ unsigned umax_(unsigned a, unsigned b) { return a > b ? a : b; }

// ---- prep: emb fp32 -> fragment-tiled bf16 embb, h2s = 0.5*||e||^2 + 1 ----
// tiled layout per 16-emb subtile (8KB): byte = (n>>4)*8192 + (c8*16 + (n&15))*16
__global__ __launch_bounds__(256) void k_prep(const float* __restrict__ emb,
                                              unsigned short* __restrict__ embb,
                                              float* __restrict__ h2s) {
  const int t = threadIdx.x;
  const int n = blockIdx.x * 8 + (t >> 5);
  const int c8 = t & 31;
  const float* src = emb + (size_t)n * 256 + c8 * 8;
  float s = 0.f;
  union { bf16x8 v; unsigned short u[8]; } pk;
#pragma unroll
  for (int i = 0; i < 8; ++i) {
    float f = src[i];
    s += f * f;
    pk.u[i] = f2bf(f);
  }
  *(bf16x8*)((char*)embb + (size_t)(n >> 4) * 8192 + (c8 * 16 + (n & 15)) * 16) = pk.v;
#pragma unroll
  for (int m = 1; m < 32; m <<= 1) s += __shfl_xor(s, m);
  if ((t & 31) == 0) h2s[n] = 0.5f * s + 1.0f;   // +1: shift scores negative
}

// ---- fused: A read once -> regs; B(all 1024 emb) streamed via LDS ring ----
// grid 512 x 256 threads (2 blocks/CU). block = 64 rows x 1024 emb.
// waves: wm=w>>1 picks 32 rows (mi=2), wn=w&1 picks 16-emb half of each tile.
__global__ __launch_bounds__(256, 2) void k_fused(
    const float* __restrict__ z, const float* __restrict__ emb,
    const unsigned short* __restrict__ embb, const float* __restrict__ h2s,
    float* __restrict__ out, float* __restrict__ acc_g,
    unsigned* __restrict__ done, float* __restrict__ lossp) {

  __shared__ __align__(16) char Lmem[66560];   // ring 4x16KB; later float[256][65]
  __shared__ __align__(16) float hL[1024];
  __shared__ unsigned kbuf[2][64];
  __shared__ float red[4];
  __shared__ int sidx[64];

  const int t = threadIdx.x;
  const int lane = t & 63;
  const int w = t >> 6;
  const int wm = w >> 1, wn = w & 1;
  const int l15 = lane & 15;
  const int l4 = lane >> 4;
  const int b = blockIdx.x >> 4;
  const int hw0 = (blockIdx.x & 15) * 64;

  // ---- phase A: z -> LDS A-tile (fragment layout), sumsq; h2s -> hL
  {
    const int hw = t & 63, cg = t >> 6;
    const float* zp = z + (size_t)b * 262144 + hw0 + hw;
    float ss = 0.f;
#pragma unroll
    for (int i = 0; i < 8; ++i) {
      const int c8 = i * 4 + cg;
      union { bf16x8 v; unsigned short u[8]; } pk;
#pragma unroll
      for (int j = 0; j < 8; ++j) {
        const float f = zp[(size_t)(c8 * 8 + j) * 1024];
        ss += f * f;
        pk.u[j] = f2bf(f);
      }
      *(bf16x8*)(Lmem + (hw >> 4) * 8192 + (c8 * 16 + (hw & 15)) * 16) = pk.v;
    }
    ((float4*)hL)[t] = *(const float4*)(h2s + t * 4);
#pragma unroll
    for (int m = 1; m < 64; m <<= 1) ss += __shfl_xor(ss, m);
    if (lane == 0) red[w] = ss;
  }
  __syncthreads();

  // ---- A-frags -> registers (rows wm*32 .. +32 : tiles 2wm, 2wm+1)
  bf16x8 af[2][8];
#pragma unroll
  for (int ti = 0; ti < 2; ++ti)
#pragma unroll
    for (int kk = 0; kk < 8; ++kk)
      af[ti][kk] = *(const bf16x8*)(Lmem + (wm * 2 + ti) * 8192 + kk * 1024 + l4 * 256 + l15 * 16);
  __syncthreads();   // A region free -> becomes ring slots 0,1

  // ---- B ring: tile = 32 embs (16KB), 4 slots, stage 3 ahead
  auto stage = [&](int s, int slot) {
    const char* src = (const char*)embb + (size_t)s * 16384;
#pragma unroll
    for (int rd = 0; rd < 4; ++rd) {
      const char* g = src + rd * 4096 + w * 1024 + lane * 16;
      char* l = Lmem + slot * 16384 + rd * 4096 + w * 1024;
      __builtin_amdgcn_global_load_lds((const __attribute__((address_space(1))) void*)g,
                                       (__attribute__((address_space(3))) void*)l,
                                       16, 0, 0);
    }
  };
  stage(0, 0); stage(1, 1); stage(2, 2);

  unsigned kb[2][4];
#pragma unroll
  for (int mi = 0; mi < 2; ++mi)
#pragma unroll
    for (int j = 0; j < 4; ++j) kb[mi][j] = 0u;
  const int ciob = 1023 - (wn * 16 + l15);

  for (int tl = 0; tl < 32; ++tl) {
    const int sn = (tl + 3 < 32) ? tl + 3 : 31;
    stage(sn, (tl + 3) & 3);
    asm volatile("s_waitcnt vmcnt(12)" ::: "memory");   // tile tl fully staged
    __builtin_amdgcn_s_barrier();

    const char* bb = Lmem + (tl & 3) * 16384 + wn * 8192;
    const float hval = hL[tl * 32 + wn * 16 + l15];
    f32x4 a0{}, a1{}, b0{}, b1{};
#pragma unroll
    for (int kk = 0; kk < 8; ++kk) {
      const bf16x8 bf = *(const bf16x8*)(bb + kk * 1024 + l4 * 256 + l15 * 16);
      if (kk < 4) {
        a0 = __builtin_amdgcn_mfma_f32_16x16x32_bf16(af[0][kk], bf, a0, 0, 0, 0);
        a1 = __builtin_amdgcn_mfma_f32_16x16x32_bf16(af[1][kk], bf, a1, 0, 0, 0);
      } else {
        b0 = __builtin_amdgcn_mfma_f32_16x16x32_bf16(af[0][kk], bf, b0, 0, 0, 0);
        b1 = __builtin_amdgcn_mfma_f32_16x16x32_bf16(af[1][kk], bf, b1, 0, 0, 0);
      }
    }
    const unsigned cio = (unsigned)(ciob - tl * 32);
#pragma unroll
    for (int j = 0; j < 4; ++j) {
      const float v0 = (a0[j] + b0[j]) - hval;     // < 0 guaranteed
      const float v1 = (a1[j] + b1[j]) - hval;
      kb[0][j] = umax_(kb[0][j], (~__float_as_uint(v0) & 0xFFFFFC00u) | cio);
      kb[1][j] = umax_(kb[1][j], (~__float_as_uint(v1) & 0xFFFFFC00u) | cio);
    }
    __builtin_amdgcn_s_barrier();   // all waves done with tile tl
  }

  // ---- final fold: 16-lane DPP reduce, merge wn pair, loss, gather+write
#pragma unroll
  for (int mi = 0; mi < 2; ++mi)
#pragma unroll
    for (int j = 0; j < 4; ++j) {
      unsigned k = kb[mi][j];
      k = umax_(k, (unsigned)__builtin_amdgcn_update_dpp(0, (int)k, 0xB1, 0xF, 0xF, true));
      k = umax_(k, (unsigned)__builtin_amdgcn_update_dpp(0, (int)k, 0x4E, 0xF, 0xF, true));
      k = umax_(k, (unsigned)__builtin_amdgcn_update_dpp(0, (int)k, 0x141, 0xF, 0xF, true));
      k = umax_(k, (unsigned)__builtin_amdgcn_update_dpp(0, (int)k, 0x140, 0xF, 0xF, true));
      if (l15 == 0) kbuf[wn][wm * 32 + mi * 16 + l4 * 4 + j] = k;
    }
  __syncthreads();
  if (t < 64) {
    const unsigned k = umax_(kbuf[0][t], kbuf[1][t]);
    sidx[t] = 1023 - (int)(k & 1023u);
    float s = __uint_as_float(~k) + 1.0f;   // best score t* = x.e - 0.5||e||^2
#pragma unroll
    for (int m = 1; m < 64; m <<= 1) s += __shfl_xor(s, m);
    if (t == 0) atomicAdd(acc_g, red[0] + red[1] + red[2] + red[3] - 2.f * s);
  }
  __syncthreads();

  // gather emb rows into float staging [c][hw], stride 65 (2-way max banks)
  float* fst = (float*)Lmem;
  {
    const int hwR = t >> 2, cq = t & 3;
    const float* ep = emb + (size_t)sidx[hwR] * 256;
#pragma unroll
    for (int s4 = 0; s4 < 4; ++s4)
#pragma unroll
      for (int f = 0; f < 4; ++f) {
        const int c0 = cq * 16 + s4 * 64 + f * 4;
        const float4 v = *(const float4*)(ep + c0);
        fst[(c0 + 0) * 65 + hwR] = v.x;
        fst[(c0 + 1) * 65 + hwR] = v.y;
        fst[(c0 + 2) * 65 + hwR] = v.z;
        fst[(c0 + 3) * 65 + hwR] = v.w;
      }
  }
  __syncthreads();
  float* ob = out + (size_t)b * 262144 + hw0;
#pragma unroll
  for (int i = 0; i < 16; ++i) {
    const int c = i * 16 + (t >> 4);
    const float4 vv = *(const float4*)(fst + c * 65 + (t & 15) * 4);
    *(float4*)(ob + (size_t)c * 1024 + (t & 15) * 4) = vv;
  }

  if (t == 0) {
    __threadfence();
    const unsigned old = atomicAdd(done, 1u);
    if (old == 511u) {
      const float tot = atomicAdd(acc_g, 0.f);
      lossp[0] = 1.25f * tot * (1.0f / 8388608.0f);
    }
  }
}

extern "C" void kernel_launch(void* const* d_in, const int* in_sizes, int n_in,
                              void* d_out, int out_size, void* d_ws, size_t ws_size,
                              hipStream_t stream) {
  (void)in_sizes; (void)n_in; (void)ws_size;
  const float* z   = (const float*)d_in[0];
  const float* emb = (const float*)d_in[1];
  float* out = (float*)d_out;
  char* ws = (char*)d_ws;
  unsigned short* embb = (unsigned short*)ws;       // 512 KB (tiled)
  float* h2s   = (float*)(ws + 524288);             // 4 KB
  float* acc   = (float*)(ws + 528384);             // 4 B
  unsigned* done = (unsigned*)(ws + 528388);        // 4 B

  hipMemsetAsync(ws + 528384, 0, 8, stream);
  hipLaunchKernelGGL(k_prep, dim3(128), dim3(256), 0, stream, emb, embb, h2s);
  hipLaunchKernelGGL(k_fused, dim3(512), dim3(256), 0, stream, z, emb, embb, h2s,
                     out, acc, done, out + (size_t)out_size - 1);
}

// Round 8
// 64.393 us; speedup vs baseline: 1.7743x; 1.1420x over previous
//
#include <hip/hip_runtime.h>
#include <stdint.h>

typedef short bf16x8 __attribute__((ext_vector_type(8)));
typedef float f32x4 __attribute__((ext_vector_type(4)));

__device__ __forceinline__ unsigned short f2bf(float f) {
  unsigned u = __float_as_uint(f);
  u += 0x7fffu + ((u >> 16) & 1u);   // RNE round to bf16
  return (unsigned short)(u >> 16);
}
__device__ __forceinline__ unsigned umax_(unsigned a, unsigned b) { return a > b ? a : b; }

// ---- prep: emb fp32 -> fragment-tiled bf16 embb, h2s = 0.5*||e||^2 + 1 ----
// per 16-emb tile (8KB): byte = (n>>4)*8192 + ((c8)*16 + (n&15))*16, c8=c/8
__global__ __launch_bounds__(256) void k_prep(const float* __restrict__ emb,
                                              unsigned short* __restrict__ embb,
                                              float* __restrict__ h2s) {
  const int t = threadIdx.x;
  const int n = blockIdx.x * 8 + (t >> 5);
  const int c8 = t & 31;
  const float* src = emb + (size_t)n * 256 + c8 * 8;
  float s = 0.f;
  union { bf16x8 v; unsigned short u[8]; } pk;
#pragma unroll
  for (int i = 0; i < 8; ++i) {
    float f = src[i];
    s += f * f;
    pk.u[i] = f2bf(f);
  }
  *(bf16x8*)((char*)embb + (size_t)(n >> 4) * 8192 + (c8 * 16 + (n & 15)) * 16) = pk.v;
#pragma unroll
  for (int m = 1; m < 32; m <<= 1) s += __shfl_xor(s, m);
  if ((t & 31) == 0) h2s[n] = 0.5f * s + 1.0f;   // +1 keeps scores strictly < 0
}

// ---- fused: A(64 rows) in regs per wave; each wave = independent pipeline
// over its private 256-emb quarter. NO barriers in the hot loop.
__global__ __launch_bounds__(256, 2) void k_fused(
    const float* __restrict__ z, const float* __restrict__ emb,
    const unsigned short* __restrict__ embb, const float* __restrict__ h2s,
    float* __restrict__ out, float* __restrict__ acc_g,
    unsigned* __restrict__ done, float* __restrict__ lossp) {

  // Lmem: phase A = 32KB A-tile; hot loop = 4 x 16KB wave-private rings;
  // epilogue = float[256][65] staging (66560 B)
  __shared__ __align__(16) char Lmem[66560];
  __shared__ __align__(16) float hL[1024];
  __shared__ unsigned kbuf[4][64];
  __shared__ float red[4];
  __shared__ int sidx[64];

  const int t = threadIdx.x;
  const int lane = t & 63;
  const int w = t >> 6;
  const int l15 = lane & 15;
  const int l4 = lane >> 4;
  const int b = blockIdx.x >> 4;
  const int hw0 = (blockIdx.x & 15) * 64;

  // ---- phase A: z -> LDS A-tile (fragment layout), sumsq; h2s -> hL
  {
    const int hw = t & 63, cg = t >> 6;
    const float* zp = z + (size_t)b * 262144 + hw0 + hw;
    float ss = 0.f;
#pragma unroll
    for (int i = 0; i < 8; ++i) {
      const int c8 = i * 4 + cg;
      union { bf16x8 v; unsigned short u[8]; } pk;
#pragma unroll
      for (int j = 0; j < 8; ++j) {
        const float f = zp[(size_t)(c8 * 8 + j) * 1024];
        ss += f * f;
        pk.u[j] = f2bf(f);
      }
      *(bf16x8*)(Lmem + (hw >> 4) * 8192 + (c8 * 16 + (hw & 15)) * 16) = pk.v;
    }
    ((float4*)hL)[t] = *(const float4*)(h2s + t * 4);
#pragma unroll
    for (int m = 1; m < 64; m <<= 1) ss += __shfl_xor(ss, m);
    if (lane == 0) red[w] = ss;
  }
  __syncthreads();

  // ---- A-frags -> registers: ALL 64 rows (4 tiles x 8 kk) per wave
  bf16x8 af[4][8];
#pragma unroll
  for (int ti = 0; ti < 4; ++ti)
#pragma unroll
    for (int kk = 0; kk < 8; ++kk)
      af[ti][kk] = *(const bf16x8*)(Lmem + ti * 8192 + kk * 1024 + l4 * 256 + l15 * 16);
  __syncthreads();   // A region freed -> becomes the 4 wave-private rings

  // ---- wave-private B ring: 2 slots x 8KB (16 embs x 256 k each)
  char* ring = Lmem + w * 16384;
  auto stage = [&](int tl, int slot) {
    const char* src = (const char*)embb + (size_t)(w * 16 + tl) * 8192;
    char* dst = ring + slot * 8192;
#pragma unroll
    for (int rd = 0; rd < 8; ++rd)
      __builtin_amdgcn_global_load_lds(
          (const __attribute__((address_space(1))) void*)(src + rd * 1024 + lane * 16),
          (__attribute__((address_space(3))) void*)(dst + rd * 1024), 16, 0, 0);
  };

  unsigned kb[4][4];
#pragma unroll
  for (int mi = 0; mi < 4; ++mi)
#pragma unroll
    for (int j = 0; j < 4; ++j) kb[mi][j] = 0u;

  stage(0, 0);
  for (int tl = 0; tl < 16; ++tl) {
    stage(tl + 1 < 16 ? tl + 1 : 15, (tl + 1) & 1);   // dummy keeps vmcnt constant
    asm volatile("s_waitcnt vmcnt(8)" ::: "memory");   // tile tl staged (per-wave)

    const char* bb = ring + (tl & 1) * 8192;
    const float hval = hL[w * 256 + tl * 16 + l15];
    f32x4 acc[4];
#pragma unroll
    for (int mi = 0; mi < 4; ++mi)
#pragma unroll
      for (int q = 0; q < 4; ++q) acc[mi][q] = 0.f;

#pragma unroll
    for (int kk = 0; kk < 8; ++kk) {
      const bf16x8 bf = *(const bf16x8*)(bb + kk * 1024 + l4 * 256 + l15 * 16);
      acc[0] = __builtin_amdgcn_mfma_f32_16x16x32_bf16(af[0][kk], bf, acc[0], 0, 0, 0);
      acc[1] = __builtin_amdgcn_mfma_f32_16x16x32_bf16(af[1][kk], bf, acc[1], 0, 0, 0);
      acc[2] = __builtin_amdgcn_mfma_f32_16x16x32_bf16(af[2][kk], bf, acc[2], 0, 0, 0);
      acc[3] = __builtin_amdgcn_mfma_f32_16x16x32_bf16(af[3][kk], bf, acc[3], 0, 0, 0);
    }
    const unsigned cio = (unsigned)(1023 - (w * 256 + tl * 16 + l15));
#pragma unroll
    for (int mi = 0; mi < 4; ++mi)
#pragma unroll
      for (int j = 0; j < 4; ++j) {
        const float v = acc[mi][j] - hval;            // strictly < 0
        kb[mi][j] = umax_(kb[mi][j], (~__float_as_uint(v) & 0xFFFFFC00u) | cio);
      }
  }

  // ---- per-wave 16-lane DPP reduce -> kbuf[w][row]
#pragma unroll
  for (int mi = 0; mi < 4; ++mi)
#pragma unroll
    for (int j = 0; j < 4; ++j) {
      unsigned k = kb[mi][j];
      k = umax_(k, (unsigned)__builtin_amdgcn_update_dpp(0, (int)k, 0xB1, 0xF, 0xF, true));
      k = umax_(k, (unsigned)__builtin_amdgcn_update_dpp(0, (int)k, 0x4E, 0xF, 0xF, true));
      k = umax_(k, (unsigned)__builtin_amdgcn_update_dpp(0, (int)k, 0x141, 0xF, 0xF, true));
      k = umax_(k, (unsigned)__builtin_amdgcn_update_dpp(0, (int)k, 0x140, 0xF, 0xF, true));
      if (l15 == 0) kbuf[w][mi * 16 + l4 * 4 + j] = k;
    }
  __syncthreads();

  // ---- merge 4 wave-quarters, loss partial
  if (t < 64) {
    unsigned k = umax_(umax_(kbuf[0][t], kbuf[1][t]), umax_(kbuf[2][t], kbuf[3][t]));
    sidx[t] = 1023 - (int)(k & 1023u);
    float s = __uint_as_float(~k) + 1.0f;   // t* = x.e - 0.5||e||^2
#pragma unroll
    for (int m = 1; m < 64; m <<= 1) s += __shfl_xor(s, m);
    if (t == 0) atomicAdd(acc_g, red[0] + red[1] + red[2] + red[3] - 2.f * s);
  }
  __syncthreads();

  // ---- gather emb rows -> LDS [c][hw] (stride 65), transposed coalesced write
  float* fst = (float*)Lmem;
  {
    const int hwR = t >> 2, cq = t & 3;
    const float* ep = emb + (size_t)sidx[hwR] * 256;
#pragma unroll
    for (int s4 = 0; s4 < 4; ++s4)
#pragma unroll
      for (int f = 0; f < 4; ++f) {
        const int c0 = cq * 16 + s4 * 64 + f * 4;
        const float4 v = *(const float4*)(ep + c0);
        fst[(c0 + 0) * 65 + hwR] = v.x;
        fst[(c0 + 1) * 65 + hwR] = v.y;
        fst[(c0 + 2) * 65 + hwR] = v.z;
        fst[(c0 + 3) * 65 + hwR] = v.w;
      }
  }
  __syncthreads();
  float* ob = out + (size_t)b * 262144 + hw0;
#pragma unroll
  for (int i = 0; i < 16; ++i) {
    const int c = i * 16 + (t >> 4);
    const float4 vv = *(const float4*)(fst + c * 65 + (t & 15) * 4);
    *(float4*)(ob + (size_t)c * 1024 + (t & 15) * 4) = vv;
  }

  if (t == 0) {
    __threadfence();
    const unsigned old = atomicAdd(done, 1u);
    if (old == 511u) {
      const float tot = atomicAdd(acc_g, 0.f);
      lossp[0] = 1.25f * tot * (1.0f / 8388608.0f);
    }
  }
}

extern "C" void kernel_launch(void* const* d_in, const int* in_sizes, int n_in,
                              void* d_out, int out_size, void* d_ws, size_t ws_size,
                              hipStream_t stream) {
  (void)in_sizes; (void)n_in; (void)ws_size;
  const float* z   = (const float*)d_in[0];
  const float* emb = (const float*)d_in[1];
  float* out = (float*)d_out;
  char* ws = (char*)d_ws;
  unsigned short* embb = (unsigned short*)ws;       // 512 KB (fragment-tiled)
  float* h2s   = (float*)(ws + 524288);             // 4 KB
  float* acc   = (float*)(ws + 528384);             // 4 B
  unsigned* done = (unsigned*)(ws + 528388);        // 4 B

  hipMemsetAsync(ws + 528384, 0, 8, stream);
  hipLaunchKernelGGL(k_prep, dim3(128), dim3(256), 0, stream, emb, embb, h2s);
  hipLaunchKernelGGL(k_fused, dim3(512), dim3(256), 0, stream, z, emb, embb, h2s,
                     out, acc, done, out + (size_t)out_size - 1);
}